// Round 20
// baseline (57.588 us; speedup 1.0000x reference)
//
#include <hip/hip_runtime.h>
#include <hip/hip_bf16.h>
#include <hip/hip_fp8.h>

#define BB 16
#define NC 64
#define NP 384
#define HH 128
#define CF 56
#define PFT 1280

typedef float f32x4 __attribute__((ext_vector_type(4)));
typedef __bf16 bf16x8 __attribute__((ext_vector_type(8)));
typedef unsigned short u16x8 __attribute__((ext_vector_type(8)));

static __device__ __forceinline__ unsigned short f2bfu(float f){
  __bf16 h = (__bf16)f;
  return __builtin_bit_cast(unsigned short, h);
}
static __device__ __forceinline__ float bfu2f(unsigned short u){
  __bf16 h = __builtin_bit_cast(__bf16, u);
  return (float)h;
}
static __device__ __forceinline__ unsigned char f2e4m3(float f){
  __hip_fp8_e4m3 h(f);
  unsigned char b;
  __builtin_memcpy(&b, &h, 1);
  return b;
}
static __device__ __forceinline__ unsigned pack4_e4m3(float4 v){
  unsigned a = f2e4m3(v.x), b = f2e4m3(v.y), c = f2e4m3(v.z), d = f2e4m3(v.w);
  return a | (b<<8) | (c<<16) | (d<<24);
}

// ---- k_prep: fused {WpT->fp8x512 | W1T | compound linear+LN | coords | dis} ----
__global__ __launch_bounds__(256) void k_prep(
    const float* __restrict__ cf, const float* __restrict__ Wc,
    const float* __restrict__ bc, const float* __restrict__ lng,
    const float* __restrict__ lnb, const float* __restrict__ Wp,
    const float* __restrict__ W1, const float* __restrict__ cc,
    const float* __restrict__ px, const float* __restrict__ dm,
    unsigned short* __restrict__ c_ln, unsigned char* __restrict__ wpt8,
    unsigned short* __restrict__ w1t,
    float* __restrict__ out1, float* __restrict__ out4, float* __restrict__ out5){
  __shared__ __align__(16) unsigned char t8[128][80];
  __shared__ float redc[2][2], redc2[2][2];
  int bx = blockIdx.x;
  int tid = threadIdx.x;
  if (bx < 20){
    int k0 = bx*64;
    #pragma unroll
    for (int i=0;i<8;i++){
      int fi = tid + i*256;
      int k  = fi>>5;
      int c4 = (fi&31)*4;
      float4 v = *(const float4*)(Wp + (size_t)(k0+k)*HH + c4);
      t8[c4+0][k]=f2e4m3(v.x*512.f); t8[c4+1][k]=f2e4m3(v.y*512.f);
      t8[c4+2][k]=f2e4m3(v.z*512.f); t8[c4+3][k]=f2e4m3(v.w*512.f);
    }
    __syncthreads();
    #pragma unroll
    for (int i=0;i<2;i++){
      int ci = tid + i*256;          // 512 16B chunks
      int col = ci>>2, kb = ci&3;
      int4 v = *(const int4*)&t8[col][kb*16];
      *(int4*)(wpt8 + (size_t)col*PFT + k0 + kb*16) = v;
    }
  } else if (bx < 84){
    int idx = (bx-20)*256+tid;
    int k = idx>>7, m = idx&127;
    w1t[m*HH+k] = f2bfu(W1[idx]);
  } else if (bx < 596){
    int rh = tid>>7, m = tid&127;
    int row = (bx-84)*2 + rh;
    const float* cr = cf + row*CF;
    float acc = bc[m];
    #pragma unroll
    for (int k=0;k<CF;k++) acc += cr[k]*Wc[k*HH+m];
    float s=acc, s2=acc*acc;
    #pragma unroll
    for (int off=1; off<64; off<<=1){ s += __shfl_xor(s,off,64); s2 += __shfl_xor(s2,off,64); }
    int wid = (tid>>6)&1;
    if ((m&63)==0){ redc[rh][wid]=s; redc2[rh][wid]=s2; }
    __syncthreads();
    float S=redc[rh][0]+redc[rh][1], S2=redc2[rh][0]+redc2[rh][1];
    float mean = S*(1.0f/HH);
    float var  = S2*(1.0f/HH) - mean*mean;
    float rs = rsqrtf(var + 1e-5f);
    c_ln[(size_t)row*HH+m] = f2bfu((acc-mean)*rs*lng[m] + lnb[m]);
  } else if (bx < 608){
    int idx = (bx-596)*256+tid;
    if (idx < BB*NC*3){
      int bb = idx/(NC*3), rem = idx%(NC*3);
      float v = cc[(size_t)bb*(2+NC+NP)*3 + 3 + rem];
      out1[idx] = (v/5.0f)*5.0f;
    }
    if (idx < BB*NC) out1[BB*NC*3+idx] = (float)(idx>>6);
  } else {
    int idx = (bx-608)*256+tid;
    int b = idx/(NP*NC), r = idx%(NP*NC), i = r>>6, j = r&63;
    const float* pp = px + ((size_t)b*NP+i)*3;
    const float* cp = cc + (size_t)b*(2+NC+NP)*3 + 3 + (size_t)j*3;
    float dx=pp[0]/5.0f-cp[0]/5.0f;
    float dy=pp[1]/5.0f-cp[1]/5.0f;
    float dz=pp[2]/5.0f-cp[2]/5.0f;
    float d = sqrtf(dx*dx+dy*dy+dz*dz)*5.0f;
    d = fminf(fmaxf(d,0.f),10.f);
    out4[idx]=d;
    out5[idx]=dm[idx];
  }
}

// ---- k_main v8: r12 structure, phase-1 in fp8 (staged bytes halved) ----
// 512 blocks x 256 thr; block (b = bx>>5, i0 = (bx&31)*12).
// Phase1: A(pf->e4m3), B(wpt8 = Wp x512 e4m3), mfma fp8_fp8, acc scaled 1/512.
// Phase2: byte-identical to r12 (bf16, sW from LDS).
__global__ __launch_bounds__(256) void k_main(
    const float* __restrict__ pf, const unsigned char* __restrict__ wpt8,
    const float* __restrict__ bp, const float* __restrict__ lng,
    const float* __restrict__ lnb,
    const unsigned short* __restrict__ c_ln, const unsigned short* __restrict__ w1t,
    const float* __restrict__ b1, const float* __restrict__ W2,
    const float* __restrict__ b2p, float* __restrict__ out3){
  __shared__ __align__(16) unsigned char uMem[32768];  // ph1: A8[2]@0/1024, B8[2]@2048/10240; ph2: sW 32KB
  __shared__ __align__(16) float sPf[12*HH];           // 6KB
  int tid = threadIdx.x;
  int w = tid>>6, lane = tid&63, q = lane&15, gr = lane>>4;
  int bx = blockIdx.x;
  int b  = bx>>5;
  int i0 = (bx&31)*12;
  size_t prow0 = (size_t)(b*NP + i0);
  // zero rows 12-15 of both A8 buffers (256 B each)
  uMem[768 + tid] = 0;
  uMem[1024 + 768 + tid] = 0;
  // ---------------- phase 1: pocket GEMM fp8 (12 rows x 1280 x 128) ----------------
  f32x4 acc2[2];
  acc2[0]=(f32x4){0.f,0.f,0.f,0.f}; acc2[1]=(f32x4){0.f,0.f,0.f,0.f};
  int arow = tid>>4, ak4 = (tid&15)*4;
  float4 ra; int4 rb8[2];
  #define LOADS1(KS) {                                                         \
    int kbase = (KS)*64;                                                       \
    if (arow < 12)                                                             \
      ra = *(const float4*)(pf + (prow0+arow)*PFT + kbase + ak4);              \
    _Pragma("unroll")                                                          \
    for (int i=0;i<2;i++){                                                     \
      int ci = tid + 256*i;                                                    \
      int col = ci>>2, kb = ci&3;                                              \
      rb8[i] = *(const int4*)(wpt8 + (size_t)col*PFT + kbase + kb*16);         \
    }                                                                          \
  }
  #define WRITES1(BUF) {                                                       \
    unsigned char* A8 = uMem + (BUF)*1024;                                     \
    unsigned char* B8 = uMem + 2048 + (BUF)*8192;                              \
    if (arow < 12)                                                             \
      *(unsigned*)(A8 + arow*64 + (((ak4>>3)^(arow&6))<<3) + (ak4&4)) = pack4_e4m3(ra); \
    _Pragma("unroll")                                                          \
    for (int i=0;i<2;i++){                                                     \
      int ci = tid + 256*i;                                                    \
      int col = ci>>2, kb = ci&3;                                              \
      *(int4*)(B8 + col*64 + (((kb*2)^(col&6))<<3)) = rb8[i];                  \
    }                                                                          \
  }
  LOADS1(0)
  WRITES1(0)
  int cur = 0;
  for (int ks=0; ks<20; ks++){
    if (ks<19) LOADS1(ks+1)
    __syncthreads();
    unsigned char* A8 = uMem + cur*1024;
    unsigned char* B8 = uMem + 2048 + cur*8192;
    #pragma unroll
    for (int kk=0;kk<2;kk++){
      long a8 = *(const long*)(A8 + q*64 + (((kk*4+gr)^(q&6))<<3));
      #pragma unroll
      for (int ct=0;ct<2;ct++){
        int col = w*32 + ct*16 + q;
        long b8 = *(const long*)(B8 + col*64 + (((kk*4+gr)^(col&6))<<3));
        acc2[ct] = __builtin_amdgcn_mfma_f32_16x16x32_fp8_fp8(a8, b8, acc2[ct], 0,0,0);
      }
    }
    if (ks<19){ WRITES1(cur^1) cur ^= 1; }
  }
  __syncthreads();
  // write GEMM result (scale 1/512, +bias) to sPf; stage W1^T into uMem (sW)
  unsigned short* sW = (unsigned short*)uMem;
  #pragma unroll
  for (int ct=0;ct<2;ct++){
    int col = w*32 + ct*16 + q;
    float bpv = bp[col];
    #pragma unroll
    for (int r=0;r<4;r++){
      int row = gr*4+r;
      if (row < 12) sPf[row*HH + col] = acc2[ct][r]*(1.0f/512.0f) + bpv;
    }
  }
  {
    const int4* srcW = (const int4*)w1t;
    #pragma unroll
    for (int i=0;i<8;i++){
      int c = tid + 256*i;
      int mm = c>>4, kb = c&15;
      ((int4*)sW)[mm*16 + (kb^(mm&7))] = srcW[c];
    }
  }
  // phase-2 invariants: c-frags packed bf16 (16 regs), b1/w2 (16 regs)
  u16x8 cfrag[4];
  {
    const unsigned short* cb = c_ln + (size_t)b*NC*HH + (size_t)(w*16+q)*HH + gr*8;
    #pragma unroll
    for (int kt=0;kt<4;kt++) cfrag[kt] = *(const u16x8*)(cb + kt*32);
  }
  float b1v[8], w2v[8];
  #pragma unroll
  for (int nt=0;nt<8;nt++){ b1v[nt]=b1[nt*16+q]; w2v[nt]=W2[nt*16+q]; }
  float b2 = b2p[0];
  __syncthreads();
  // ---------------- LN over the 12 rows (wave w -> rows w*3..w*3+2) ----------------
  {
    float g0 = lng[lane], g1 = lng[lane+64];
    float B0 = lnb[lane], B1 = lnb[lane+64];
    #pragma unroll
    for (int rr=0; rr<3; rr++){
      int row = w*3+rr;
      float a0 = sPf[row*HH + lane], a1 = sPf[row*HH + lane + 64];
      float s = a0+a1, s2 = a0*a0 + a1*a1;
      #pragma unroll
      for (int off=1; off<64; off<<=1){ s += __shfl_xor(s,off,64); s2 += __shfl_xor(s2,off,64); }
      float mean = s*(1.0f/HH);
      float var  = s2*(1.0f/HH) - mean*mean;
      float rs   = rsqrtf(var + 1e-5f);
      sPf[row*HH + lane]      = (a0-mean)*rs*g0 + B0;
      sPf[row*HH + lane + 64] = (a1-mean)*rs*g1 + B1;
    }
  }
  __syncthreads();
  // ---------------- phase 2: pairwise MLP over 12 i-rows, B-frags from LDS ----------------
  for (int ii=0; ii<12; ii++){
    f32x4 acc[8];
    #pragma unroll
    for (int nt=0;nt<8;nt++) acc[nt]=(f32x4){0.f,0.f,0.f,0.f};
    #pragma unroll
    for (int kt=0;kt<4;kt++){
      int kblk = kt*4+gr;
      f32x4 p0 = *(const f32x4*)&sPf[ii*HH + kblk*8];
      f32x4 p1 = *(const f32x4*)&sPf[ii*HH + kblk*8 + 4];
      u16x8 cfv = cfrag[kt];
      bf16x8 a;
      #pragma unroll
      for (int e=0;e<4;e++) a[e]   = (__bf16)(bfu2f(cfv[e])*p0[e]);
      #pragma unroll
      for (int e=0;e<4;e++) a[e+4] = (__bf16)(bfu2f(cfv[e+4])*p1[e]);
      #pragma unroll
      for (int nt=0;nt<8;nt++){
        int mm = nt*16+q;
        bf16x8 bv = *(const bf16x8*)&sW[mm*HH + ((kblk^(mm&7))<<3)];
        acc[nt] = __builtin_amdgcn_mfma_f32_16x16x32_bf16(a, bv, acc[nt], 0,0,0);
      }
    }
    float part[4]={0.f,0.f,0.f,0.f};
    #pragma unroll
    for (int nt=0;nt<8;nt++)
      #pragma unroll
      for (int r=0;r<4;r++){
        float h = acc[nt][r] + b1v[nt];
        h = fmaxf(h, 0.f);
        part[r] += h*w2v[nt];
      }
    #pragma unroll
    for (int r=0;r<4;r++){
      part[r]+=__shfl_xor(part[r],1,16);
      part[r]+=__shfl_xor(part[r],2,16);
      part[r]+=__shfl_xor(part[r],4,16);
      part[r]+=__shfl_xor(part[r],8,16);
    }
    if (q==0){
      float4 o;
      o.x = 10.f/(1.f+expf(-(part[0]+b2)));
      o.y = 10.f/(1.f+expf(-(part[1]+b2)));
      o.z = 10.f/(1.f+expf(-(part[2]+b2)));
      o.w = 10.f/(1.f+expf(-(part[3]+b2)));
      *(float4*)(out3 + (prow0+ii)*NC + w*16 + gr*4) = o;
    }
  }
}

extern "C" void kernel_launch(void* const* d_in, const int* in_sizes, int n_in,
                              void* d_out, int out_size, void* d_ws, size_t ws_size,
                              hipStream_t stream){
  const float* cf = (const float*)d_in[0];
  const float* pf = (const float*)d_in[1];
  const float* cc = (const float*)d_in[2];
  const float* px = (const float*)d_in[3];
  const float* dm = (const float*)d_in[4];
  const float* Wc = (const float*)d_in[5];
  const float* bc = (const float*)d_in[6];
  const float* Wp = (const float*)d_in[7];
  const float* bp = (const float*)d_in[8];
  const float* lng= (const float*)d_in[9];
  const float* lnb= (const float*)d_in[10];
  const float* W1 = (const float*)d_in[11];
  const float* b1 = (const float*)d_in[12];
  const float* W2 = (const float*)d_in[13];
  const float* b2 = (const float*)d_in[14];

  float* out = (float*)d_out;
  char* ws = (char*)d_ws;
  unsigned short* c_ln = (unsigned short*)ws;                      // 262144 B
  unsigned short* w1t  = (unsigned short*)(ws + 262144 + 1572864); // 32768 B
  unsigned char*  wpt8 = (unsigned char*)(ws + 262144 + 1572864 + 32768); // 163840 B (fp8)

  float* out1 = out;
  float* out3 = out + BB*NC*3 + BB*NC;
  float* out4 = out3 + BB*NP*NC;
  float* out5 = out4 + BB*NP*NC;

  hipLaunchKernelGGL(k_prep, dim3(2144), dim3(256), 0, stream,
                     cf, Wc, bc, lng, lnb, Wp, W1, cc, px, dm,
                     c_ln, wpt8, w1t, out1, out4, out5);
  hipLaunchKernelGGL(k_main, dim3(512), dim3(256), 0, stream,
                     pf, wpt8, bp, lng, lnb, c_ln, w1t, b1, W2, b2, out3);
}

// Round 21
// 41.751 us; speedup vs baseline: 1.3793x; 1.3793x over previous
//
#include <hip/hip_runtime.h>
#include <hip/hip_bf16.h>

#define BB 16
#define NC 64
#define NP 384
#define HH 128
#define CF 56
#define PFT 1280

typedef float f32x4 __attribute__((ext_vector_type(4)));
typedef __bf16 bf16x8 __attribute__((ext_vector_type(8)));
typedef unsigned short u16x8 __attribute__((ext_vector_type(8)));
typedef unsigned short u16x4 __attribute__((ext_vector_type(4)));

static __device__ __forceinline__ unsigned short f2bfu(float f){
  __bf16 h = (__bf16)f;
  return __builtin_bit_cast(unsigned short, h);
}
static __device__ __forceinline__ float bfu2f(unsigned short u){
  __bf16 h = __builtin_bit_cast(__bf16, u);
  return (float)h;
}

// ---- k_prep: fused {WpT transpose | W1T | compound linear+LN | coords | dis} ----
__global__ __launch_bounds__(256) void k_prep(
    const float* __restrict__ cf, const float* __restrict__ Wc,
    const float* __restrict__ bc, const float* __restrict__ lng,
    const float* __restrict__ lnb, const float* __restrict__ Wp,
    const float* __restrict__ W1, const float* __restrict__ cc,
    const float* __restrict__ px, const float* __restrict__ dm,
    unsigned short* __restrict__ c_ln, unsigned short* __restrict__ wpt,
    unsigned short* __restrict__ w1t,
    float* __restrict__ out1, float* __restrict__ out4, float* __restrict__ out5){
  __shared__ unsigned short t[128][72];
  __shared__ float redc[2][2], redc2[2][2];
  int bx = blockIdx.x;
  int tid = threadIdx.x;
  if (bx < 20){
    int k0 = bx*64;
    #pragma unroll
    for (int i=0;i<8;i++){
      int fi = tid + i*256;
      int k  = fi>>5;
      int c4 = (fi&31)*4;
      float4 v = *(const float4*)(Wp + (size_t)(k0+k)*HH + c4);
      t[c4+0][k]=f2bfu(v.x); t[c4+1][k]=f2bfu(v.y);
      t[c4+2][k]=f2bfu(v.z); t[c4+3][k]=f2bfu(v.w);
    }
    __syncthreads();
    #pragma unroll
    for (int i=0;i<4;i++){
      int ci = tid + i*256;
      int col = ci>>3, kb = ci&7;
      u16x8 v = *(const u16x8*)&t[col][kb*8];
      *(u16x8*)(wpt + (size_t)col*PFT + k0 + kb*8) = v;
    }
  } else if (bx < 84){
    int idx = (bx-20)*256+tid;
    int k = idx>>7, m = idx&127;
    w1t[m*HH+k] = f2bfu(W1[idx]);
  } else if (bx < 596){
    int rh = tid>>7, m = tid&127;
    int row = (bx-84)*2 + rh;
    const float* cr = cf + row*CF;
    float acc = bc[m];
    #pragma unroll
    for (int k=0;k<CF;k++) acc += cr[k]*Wc[k*HH+m];
    float s=acc, s2=acc*acc;
    #pragma unroll
    for (int off=1; off<64; off<<=1){ s += __shfl_xor(s,off,64); s2 += __shfl_xor(s2,off,64); }
    int wid = (tid>>6)&1;
    if ((m&63)==0){ redc[rh][wid]=s; redc2[rh][wid]=s2; }
    __syncthreads();
    float S=redc[rh][0]+redc[rh][1], S2=redc2[rh][0]+redc2[rh][1];
    float mean = S*(1.0f/HH);
    float var  = S2*(1.0f/HH) - mean*mean;
    float rs = rsqrtf(var + 1e-5f);
    c_ln[(size_t)row*HH+m] = f2bfu((acc-mean)*rs*lng[m] + lnb[m]);
  } else if (bx < 608){
    int idx = (bx-596)*256+tid;
    if (idx < BB*NC*3){
      int bb = idx/(NC*3), rem = idx%(NC*3);
      float v = cc[(size_t)bb*(2+NC+NP)*3 + 3 + rem];
      out1[idx] = (v/5.0f)*5.0f;
    }
    if (idx < BB*NC) out1[BB*NC*3+idx] = (float)(idx>>6);
  } else {
    int idx = (bx-608)*256+tid;
    int b = idx/(NP*NC), r = idx%(NP*NC), i = r>>6, j = r&63;
    const float* pp = px + ((size_t)b*NP+i)*3;
    const float* cp = cc + (size_t)b*(2+NC+NP)*3 + 3 + (size_t)j*3;
    float dx=pp[0]/5.0f-cp[0]/5.0f;
    float dy=pp[1]/5.0f-cp[1]/5.0f;
    float dz=pp[2]/5.0f-cp[2]/5.0f;
    float d = sqrtf(dx*dx+dy*dy+dz*dz)*5.0f;
    d = fminf(fmaxf(d,0.f),10.f);
    out4[idx]=d;
    out5[idx]=dm[idx];
  }
}

// ---- k_main v9: r12 structure with BK=128 (10 K-steps, half the barriers) ----
// 512 blocks x 256 thr; block (b = bx>>5, i0 = (bx&31)*12).
// LDS: sA 2x4KB + sB 2x32KB (sW unions into sB) + sPf 6KB = 78KB -> 2 blocks/CU.
__global__ __launch_bounds__(256) void k_main(
    const float* __restrict__ pf, const unsigned short* __restrict__ wpt,
    const float* __restrict__ bp, const float* __restrict__ lng,
    const float* __restrict__ lnb,
    const unsigned short* __restrict__ c_ln, const unsigned short* __restrict__ w1t,
    const float* __restrict__ b1, const float* __restrict__ W2,
    const float* __restrict__ b2p, float* __restrict__ out3){
  __shared__ __align__(16) unsigned short sA[2][16*128];   // 4KB each, rows 12-15 zero
  __shared__ __align__(16) unsigned short sB[2][HH*128];   // 32KB each; phase2: sW1 32KB
  __shared__ __align__(16) float sPf[12*HH];               // 6KB
  int tid = threadIdx.x;
  int w = tid>>6, lane = tid&63, q = lane&15, gr = lane>>4;
  int bx = blockIdx.x;
  int b  = bx>>5;
  int i0 = (bx&31)*12;
  size_t prow0 = (size_t)(b*NP + i0);
  // zero pad rows 12-15 of both A buffers (1KB each = 256 u16x2)
  *(unsigned*)((char*)&sA[0][0] + 3072 + tid*4) = 0;
  *(unsigned*)((char*)&sA[1][0] + 3072 + tid*4) = 0;
  // ---------------- phase 1: pocket GEMM (12 rows x 1280 x 128), BK=128 ----------------
  f32x4 acc2[2];
  acc2[0]=(f32x4){0.f,0.f,0.f,0.f}; acc2[1]=(f32x4){0.f,0.f,0.f,0.f};
  float4 ra[2]; u16x8 rb[8];
  // A staging: 384 float4 (12 rows x 32 k4); thread covers fi = tid, tid+256
  #define LOADS1(KS) {                                                         \
    int kbase = (KS)*128;                                                      \
    _Pragma("unroll")                                                          \
    for (int i=0;i<2;i++){                                                     \
      int fi = tid + 256*i;                                                    \
      if (fi < 384){                                                           \
        int row = fi>>5, k4 = (fi&31)*4;                                       \
        ra[i] = *(const float4*)(pf + (prow0+row)*PFT + kbase + k4);           \
      }                                                                        \
    }                                                                          \
    _Pragma("unroll")                                                          \
    for (int i=0;i<8;i++){                                                     \
      int ci = tid + 256*i;                                                    \
      int col = ci>>4, kb = ci&15;                                             \
      rb[i] = *(const u16x8*)(wpt + (size_t)col*PFT + kbase + kb*8);           \
    }                                                                          \
  }
  #define WRITES1(BUF) {                                                       \
    char* A = (char*)&sA[BUF][0];                                              \
    char* Bc = (char*)&sB[BUF][0];                                             \
    _Pragma("unroll")                                                          \
    for (int i=0;i<2;i++){                                                     \
      int fi = tid + 256*i;                                                    \
      if (fi < 384){                                                           \
        int row = fi>>5, k4 = (fi&31)*4;                                       \
        u16x4 h = { f2bfu(ra[i].x), f2bfu(ra[i].y), f2bfu(ra[i].z), f2bfu(ra[i].w) }; \
        *(u16x4*)(A + row*256 + (((k4>>3)^(row&15))<<4) + ((k4&7)<<1)) = h;    \
      }                                                                        \
    }                                                                          \
    _Pragma("unroll")                                                          \
    for (int i=0;i<8;i++){                                                     \
      int ci = tid + 256*i;                                                    \
      int col = ci>>4, kb = ci&15;                                             \
      *(u16x8*)(Bc + col*256 + ((kb^(col&15))<<4)) = rb[i];                    \
    }                                                                          \
  }
  LOADS1(0)
  WRITES1(0)
  int cur = 0;
  for (int ks=0; ks<10; ks++){
    if (ks<9) LOADS1(ks+1)
    __syncthreads();
    char* A = (char*)&sA[cur][0];
    char* Bc = (char*)&sB[cur][0];
    #pragma unroll
    for (int kk=0;kk<4;kk++){
      bf16x8 a = *(bf16x8*)(A + q*256 + (((kk*4+gr)^(q&15))<<4));
      #pragma unroll
      for (int ct=0;ct<2;ct++){
        int col = w*32 + ct*16 + q;
        bf16x8 bfr = *(bf16x8*)(Bc + col*256 + (((kk*4+gr)^(col&15))<<4));
        acc2[ct] = __builtin_amdgcn_mfma_f32_16x16x32_bf16(a,bfr,acc2[ct],0,0,0);
      }
    }
    if (ks<9){ WRITES1(cur^1) cur ^= 1; }
  }
  __syncthreads();
  // write GEMM result (+bias) to sPf; stage W1^T into sB[0] area (sW1, r12 layout)
  unsigned short* sW = &sB[0][0];
  #pragma unroll
  for (int ct=0;ct<2;ct++){
    int col = w*32 + ct*16 + q;
    float bpv = bp[col];
    #pragma unroll
    for (int r=0;r<4;r++){
      int row = gr*4+r;
      if (row < 12) sPf[row*HH + col] = acc2[ct][r] + bpv;
    }
  }
  {
    const int4* srcW = (const int4*)w1t;
    #pragma unroll
    for (int i=0;i<8;i++){
      int c = tid + 256*i;
      int mm = c>>4, kb = c&15;
      ((int4*)sW)[mm*16 + (kb^(mm&7))] = srcW[c];
    }
  }
  // phase-2 invariants: c-frags packed bf16 (16 regs), b1/w2 (16 regs)
  u16x8 cfrag[4];
  {
    const unsigned short* cb = c_ln + (size_t)b*NC*HH + (size_t)(w*16+q)*HH + gr*8;
    #pragma unroll
    for (int kt=0;kt<4;kt++) cfrag[kt] = *(const u16x8*)(cb + kt*32);
  }
  float b1v[8], w2v[8];
  #pragma unroll
  for (int nt=0;nt<8;nt++){ b1v[nt]=b1[nt*16+q]; w2v[nt]=W2[nt*16+q]; }
  float b2 = b2p[0];
  __syncthreads();
  // ---------------- LN over the 12 rows (wave w -> rows w*3..w*3+2) ----------------
  {
    float g0 = lng[lane], g1 = lng[lane+64];
    float B0 = lnb[lane], B1 = lnb[lane+64];
    #pragma unroll
    for (int rr=0; rr<3; rr++){
      int row = w*3+rr;
      float a0 = sPf[row*HH + lane], a1 = sPf[row*HH + lane + 64];
      float s = a0+a1, s2 = a0*a0 + a1*a1;
      #pragma unroll
      for (int off=1; off<64; off<<=1){ s += __shfl_xor(s,off,64); s2 += __shfl_xor(s2,off,64); }
      float mean = s*(1.0f/HH);
      float var  = s2*(1.0f/HH) - mean*mean;
      float rs   = rsqrtf(var + 1e-5f);
      sPf[row*HH + lane]      = (a0-mean)*rs*g0 + B0;
      sPf[row*HH + lane + 64] = (a1-mean)*rs*g1 + B1;
    }
  }
  __syncthreads();
  // ---------------- phase 2: pairwise MLP over 12 i-rows, B-frags from LDS ----------------
  for (int ii=0; ii<12; ii++){
    f32x4 acc[8];
    #pragma unroll
    for (int nt=0;nt<8;nt++) acc[nt]=(f32x4){0.f,0.f,0.f,0.f};
    #pragma unroll
    for (int kt=0;kt<4;kt++){
      int kblk = kt*4+gr;
      f32x4 p0 = *(const f32x4*)&sPf[ii*HH + kblk*8];
      f32x4 p1 = *(const f32x4*)&sPf[ii*HH + kblk*8 + 4];
      u16x8 cfv = cfrag[kt];
      bf16x8 a;
      #pragma unroll
      for (int e=0;e<4;e++) a[e]   = (__bf16)(bfu2f(cfv[e])*p0[e]);
      #pragma unroll
      for (int e=0;e<4;e++) a[e+4] = (__bf16)(bfu2f(cfv[e+4])*p1[e]);
      #pragma unroll
      for (int nt=0;nt<8;nt++){
        int mm = nt*16+q;
        bf16x8 bv = *(const bf16x8*)&sW[mm*HH + ((kblk^(mm&7))<<3)];
        acc[nt] = __builtin_amdgcn_mfma_f32_16x16x32_bf16(a, bv, acc[nt], 0,0,0);
      }
    }
    float part[4]={0.f,0.f,0.f,0.f};
    #pragma unroll
    for (int nt=0;nt<8;nt++)
      #pragma unroll
      for (int r=0;r<4;r++){
        float h = acc[nt][r] + b1v[nt];
        h = fmaxf(h, 0.f);
        part[r] += h*w2v[nt];
      }
    #pragma unroll
    for (int r=0;r<4;r++){
      part[r]+=__shfl_xor(part[r],1,16);
      part[r]+=__shfl_xor(part[r],2,16);
      part[r]+=__shfl_xor(part[r],4,16);
      part[r]+=__shfl_xor(part[r],8,16);
    }
    if (q==0){
      float4 o;
      o.x = 10.f/(1.f+expf(-(part[0]+b2)));
      o.y = 10.f/(1.f+expf(-(part[1]+b2)));
      o.z = 10.f/(1.f+expf(-(part[2]+b2)));
      o.w = 10.f/(1.f+expf(-(part[3]+b2)));
      *(float4*)(out3 + (prow0+ii)*NC + w*16 + gr*4) = o;
    }
  }
}

extern "C" void kernel_launch(void* const* d_in, const int* in_sizes, int n_in,
                              void* d_out, int out_size, void* d_ws, size_t ws_size,
                              hipStream_t stream){
  const float* cf = (const float*)d_in[0];
  const float* pf = (const float*)d_in[1];
  const float* cc = (const float*)d_in[2];
  const float* px = (const float*)d_in[3];
  const float* dm = (const float*)d_in[4];
  const float* Wc = (const float*)d_in[5];
  const float* bc = (const float*)d_in[6];
  const float* Wp = (const float*)d_in[7];
  const float* bp = (const float*)d_in[8];
  const float* lng= (const float*)d_in[9];
  const float* lnb= (const float*)d_in[10];
  const float* W1 = (const float*)d_in[11];
  const float* b1 = (const float*)d_in[12];
  const float* W2 = (const float*)d_in[13];
  const float* b2 = (const float*)d_in[14];

  float* out = (float*)d_out;
  char* ws = (char*)d_ws;
  unsigned short* c_ln = (unsigned short*)ws;                      // 262144 B
  unsigned short* w1t  = (unsigned short*)(ws + 262144 + 1572864); // 32768 B
  unsigned short* wpt  = (unsigned short*)(ws + 262144 + 1572864 + 32768); // 327680 B

  float* out1 = out;
  float* out3 = out + BB*NC*3 + BB*NC;
  float* out4 = out3 + BB*NP*NC;
  float* out5 = out4 + BB*NP*NC;

  hipLaunchKernelGGL(k_prep, dim3(2144), dim3(256), 0, stream,
                     cf, Wc, bc, lng, lnb, Wp, W1, cc, px, dm,
                     c_ln, wpt, w1t, out1, out4, out5);
  hipLaunchKernelGGL(k_main, dim3(512), dim3(256), 0, stream,
                     pf, wpt, bp, lng, lnb, c_ln, w1t, b1, W2, b2, out3);
}